// Round 1
// baseline (1586.680 us; speedup 1.0000x reference)
//
#include <hip/hip_runtime.h>

#define N_NODES 20000
#define DEG 16
#define GRAPHS 16
#define NPG 1250   // nodes per graph (20000/16)

// ---------------- conv1: msg=[pos_src, pos_src-pos_dst] (6) -> 128 -> relu -> 128, max over 16 edges
__global__ __launch_bounds__(128) void conv1_kernel(
    const float* __restrict__ pos, const int* __restrict__ esrc,
    const float* __restrict__ W1, const float* __restrict__ b1,
    const float* __restrict__ W2, const float* __restrict__ b2,
    float* __restrict__ x1)
{
    __shared__ float msg[DEG][6];
    __shared__ float hid[DEG][128];
    const int node = blockIdx.x;
    const int c = threadIdx.x;

    if (c < DEG) {
        int s = esrc[node * DEG + c];
        float px = pos[3*s],    py = pos[3*s+1],    pz = pos[3*s+2];
        float dx = pos[3*node], dy = pos[3*node+1], dz = pos[3*node+2];
        msg[c][0] = px;      msg[c][1] = py;      msg[c][2] = pz;
        msg[c][3] = px - dx; msg[c][4] = py - dy; msg[c][5] = pz - dz;
    }
    __syncthreads();

    // layer 1: hid[e][c] = relu(b1[c] + sum_k msg[e][k]*W1[k,c])
    float w1r[6];
    #pragma unroll
    for (int k = 0; k < 6; k++) w1r[k] = W1[k*128 + c];
    float bb = b1[c];
    #pragma unroll
    for (int e = 0; e < DEG; e++) {
        float h = bb;
        #pragma unroll
        for (int k = 0; k < 6; k++) h += msg[e][k] * w1r[k];
        hid[e][c] = fmaxf(h, 0.0f);
    }
    __syncthreads();

    // layer 2 + max over edges
    float acc[DEG];
    float b2c = b2[c];
    #pragma unroll
    for (int e = 0; e < DEG; e++) acc[e] = b2c;
    for (int k = 0; k < 128; k += 4) {
        float w0 = W2[(k+0)*128 + c];
        float w1_ = W2[(k+1)*128 + c];
        float w2_ = W2[(k+2)*128 + c];
        float w3 = W2[(k+3)*128 + c];
        #pragma unroll
        for (int e = 0; e < DEG; e++) {
            float4 h4 = *(const float4*)&hid[e][k];
            acc[e] += h4.x*w0 + h4.y*w1_ + h4.z*w2_ + h4.w*w3;
        }
    }
    float m = acc[0];
    #pragma unroll
    for (int e = 1; e < DEG; e++) m = fmaxf(m, acc[e]);
    x1[node*128 + c] = m;
}

// ---------------- conv2: msg=[x1_src (128), rel (3)] -> 256 -> relu -> 256, max over edges,
//                  fused global max-pool via monotone-uint atomicMax
__global__ __launch_bounds__(256) void conv2_kernel(
    const float* __restrict__ pos, const int* __restrict__ esrc,
    const float* __restrict__ x1,
    const float* __restrict__ W1, const float* __restrict__ b1,
    const float* __restrict__ W2, const float* __restrict__ b2,
    unsigned int* __restrict__ pooled)
{
    __shared__ int   ssrc[DEG];
    __shared__ float rel[DEG][3];
    __shared__ float xin[DEG][128];
    __shared__ float hid[DEG][256];
    const int node = blockIdx.x;
    const int c = threadIdx.x;

    if (c < DEG) {
        int s = esrc[node * DEG + c];
        ssrc[c] = s;
        rel[c][0] = pos[3*s]   - pos[3*node];
        rel[c][1] = pos[3*s+1] - pos[3*node+1];
        rel[c][2] = pos[3*s+2] - pos[3*node+2];
    }
    __syncthreads();

    // gather x1 rows for the 16 srcs (coalesced 512B per half-block)
    {
        const int e0 = c >> 7;      // 0/1
        const int k  = c & 127;
        #pragma unroll
        for (int r = 0; r < 8; r++) {
            int e = r*2 + e0;
            xin[e][k] = x1[(size_t)ssrc[e]*128 + k];
        }
    }
    __syncthreads();

    // layer 1: 131 -> 256
    float acc[DEG];
    float bb = b1[c];
    #pragma unroll
    for (int e = 0; e < DEG; e++) acc[e] = bb;
    for (int k = 0; k < 128; k += 4) {
        float w0 = W1[(k+0)*256 + c];
        float w1_ = W1[(k+1)*256 + c];
        float w2_ = W1[(k+2)*256 + c];
        float w3 = W1[(k+3)*256 + c];
        #pragma unroll
        for (int e = 0; e < DEG; e++) {
            float4 h4 = *(const float4*)&xin[e][k];
            acc[e] += h4.x*w0 + h4.y*w1_ + h4.z*w2_ + h4.w*w3;
        }
    }
    {   // rel features, rows 128..130
        float w0 = W1[128*256 + c], w1_ = W1[129*256 + c], w2_ = W1[130*256 + c];
        #pragma unroll
        for (int e = 0; e < DEG; e++)
            acc[e] += rel[e][0]*w0 + rel[e][1]*w1_ + rel[e][2]*w2_;
    }
    #pragma unroll
    for (int e = 0; e < DEG; e++) hid[e][c] = fmaxf(acc[e], 0.0f);
    __syncthreads();

    // layer 2: 256 -> 256
    float b2c = b2[c];
    #pragma unroll
    for (int e = 0; e < DEG; e++) acc[e] = b2c;
    for (int k = 0; k < 256; k += 4) {
        float w0 = W2[(k+0)*256 + c];
        float w1_ = W2[(k+1)*256 + c];
        float w2_ = W2[(k+2)*256 + c];
        float w3 = W2[(k+3)*256 + c];
        #pragma unroll
        for (int e = 0; e < DEG; e++) {
            float4 h4 = *(const float4*)&hid[e][k];
            acc[e] += h4.x*w0 + h4.y*w1_ + h4.z*w2_ + h4.w*w3;
        }
    }
    float m = acc[0];
    #pragma unroll
    for (int e = 1; e < DEG; e++) m = fmaxf(m, acc[e]);

    // monotone float->uint, then device-scope atomicMax into per-graph pool
    unsigned u = __float_as_uint(m);
    u = (u & 0x80000000u) ? ~u : (u | 0x80000000u);
    atomicMax(&pooled[(node / NPG)*256 + c], u);
}

// ---------------- head: pooled[16,256] -> fc1(relu) -> fc2(relu) -> labels[16,10] ++ bbox[16,6]
__global__ __launch_bounds__(256) void head_kernel(
    const unsigned int* __restrict__ pooled,
    const float* __restrict__ fc1_W, const float* __restrict__ fc1_b,
    const float* __restrict__ fc2_W, const float* __restrict__ fc2_b,
    const float* __restrict__ lab_W, const float* __restrict__ lab_b,
    const float* __restrict__ box_W, const float* __restrict__ box_b,
    float* __restrict__ out)
{
    __shared__ float p [GRAPHS][256];
    __shared__ float h1[GRAPHS][256];
    __shared__ float h2[GRAPHS][128];
    const int c = threadIdx.x;

    #pragma unroll
    for (int g = 0; g < GRAPHS; g++) {
        unsigned u = pooled[g*256 + c];
        u = (u & 0x80000000u) ? (u & 0x7fffffffu) : ~u;
        p[g][c] = __uint_as_float(u);
    }
    __syncthreads();

    float acc[GRAPHS];
    float bb = fc1_b[c];
    #pragma unroll
    for (int g = 0; g < GRAPHS; g++) acc[g] = bb;
    for (int k = 0; k < 256; k++) {
        float w = fc1_W[k*256 + c];
        #pragma unroll
        for (int g = 0; g < GRAPHS; g++) acc[g] += p[g][k] * w;
    }
    #pragma unroll
    for (int g = 0; g < GRAPHS; g++) h1[g][c] = fmaxf(acc[g], 0.0f);
    __syncthreads();

    if (c < 128) {
        float bb2 = fc2_b[c];
        #pragma unroll
        for (int g = 0; g < GRAPHS; g++) acc[g] = bb2;
        for (int k = 0; k < 256; k++) {
            float w = fc2_W[k*128 + c];
            #pragma unroll
            for (int g = 0; g < GRAPHS; g++) acc[g] += h1[g][k] * w;
        }
        #pragma unroll
        for (int g = 0; g < GRAPHS; g++) h2[g][c] = fmaxf(acc[g], 0.0f);
    }
    __syncthreads();

    if (c < 160) {
        int g = c / 10, j = c % 10;
        float a = lab_b[j];
        for (int k = 0; k < 128; k++) a += h2[g][k] * lab_W[k*10 + j];
        out[c] = a;
    } else {
        int t = c - 160;           // 0..95
        int g = t / 6, j = t % 6;
        float a = box_b[j];
        for (int k = 0; k < 128; k++) a += h2[g][k] * box_W[k*6 + j];
        out[160 + t] = a;
    }
}

extern "C" void kernel_launch(void* const* d_in, const int* in_sizes, int n_in,
                              void* d_out, int out_size, void* d_ws, size_t ws_size,
                              hipStream_t stream) {
    const float* pos   = (const float*)d_in[0];
    const int*   esrc  = (const int*)  d_in[1];
    // d_in[2] edge_dst == repeat(arange(N),16)  (implicit: dst = edge>>4)
    // d_in[3] batch    == node/1250            (implicit)
    const float* c1W1 = (const float*)d_in[4];
    const float* c1b1 = (const float*)d_in[5];
    const float* c1W2 = (const float*)d_in[6];
    const float* c1b2 = (const float*)d_in[7];
    const float* c2W1 = (const float*)d_in[8];
    const float* c2b1 = (const float*)d_in[9];
    const float* c2W2 = (const float*)d_in[10];
    const float* c2b2 = (const float*)d_in[11];
    const float* fc1W = (const float*)d_in[12];
    const float* fc1b = (const float*)d_in[13];
    const float* fc2W = (const float*)d_in[14];
    const float* fc2b = (const float*)d_in[15];
    const float* labW = (const float*)d_in[16];
    const float* labb = (const float*)d_in[17];
    const float* boxW = (const float*)d_in[18];
    const float* boxb = (const float*)d_in[19];

    float* x1 = (float*)d_ws;                                        // 20000*128 f32 = 10.24 MB
    unsigned int* pooled = (unsigned int*)((char*)d_ws + (size_t)N_NODES*128*sizeof(float)); // 16 KB

    // pooled must be re-initialized every call (ws is re-poisoned); 0 == flipped(-inf)
    hipMemsetAsync(pooled, 0, GRAPHS*256*sizeof(unsigned int), stream);

    conv1_kernel<<<N_NODES, 128, 0, stream>>>(pos, esrc, c1W1, c1b1, c1W2, c1b2, x1);
    conv2_kernel<<<N_NODES, 256, 0, stream>>>(pos, esrc, x1, c2W1, c2b1, c2W2, c2b2, pooled);
    head_kernel<<<1, 256, 0, stream>>>(pooled, fc1W, fc1b, fc2W, fc2b,
                                       labW, labb, boxW, boxb, (float*)d_out);
}

// Round 2
// 357.288 us; speedup vs baseline: 4.4409x; 4.4409x over previous
//
#include <hip/hip_runtime.h>

#define N_NODES 20000
#define DEG 16
#define GRAPHS 16
#define NPG 1250

typedef __bf16 bf16x8 __attribute__((ext_vector_type(8)));
typedef float f32x4 __attribute__((ext_vector_type(4)));
#define MFMA16(a, b, c) __builtin_amdgcn_mfma_f32_16x16x32_bf16(a, b, c, 0, 0, 0)

// ---- workspace layout (bf16 element offsets) ----
// x1      : [20000][128] bf16                       @ 0
// c1W1p   : MT=8  KT=1  -> 4096                     @ 2560000
// c1W2p   : MT=8  KT=4  -> 16384                    @ 2564096
// c2W1p   : MT=16 KT=5  -> 40960                    @ 2580480
// c2W2p   : MT=16 KT=8  -> 65536                    @ 2621440
// pooled  : 16*256 u32                              @ byte 5373952
#define OFF_X1    0
#define OFF_P1    2560000
#define OFF_P2    2564096
#define OFF_P3    2580480
#define OFF_P4    2621440
#define OFF_POOL_BYTES 5373952

// Pack W[k][m] (row-major [K][M]) into A-fragment layout for mfma_f32_16x16x32_bf16:
// packed[((mt*KT+kt)*64+lane)*8 + j] = W[k][m], m=mt*16+(lane&15), k=kt*32+(lane>>4)*8+j, 0 if k>=Kreal
__global__ __launch_bounds__(256) void pack_weights(
    const float* __restrict__ c1W1, const float* __restrict__ c1W2,
    const float* __restrict__ c2W1, const float* __restrict__ c2W2,
    __bf16* __restrict__ p1, __bf16* __restrict__ p2,
    __bf16* __restrict__ p3, __bf16* __restrict__ p4)
{
    int t = blockIdx.x * 256 + threadIdx.x;
    const float* W; __bf16* out; int M, Kreal, KT, loc;
    if      (t <   4096) { W = c1W1; out = p1; M = 128; Kreal =   6; KT = 1; loc = t; }
    else if (t <  20480) { W = c1W2; out = p2; M = 128; Kreal = 128; KT = 4; loc = t - 4096; }
    else if (t <  61440) { W = c2W1; out = p3; M = 256; Kreal = 131; KT = 5; loc = t - 20480; }
    else if (t < 126976) { W = c2W2; out = p4; M = 256; Kreal = 256; KT = 8; loc = t - 61440; }
    else return;
    int j = loc & 7, lane = (loc >> 3) & 63, rest = loc >> 9;
    int kt = rest % KT, mt = rest / KT;
    int m = mt * 16 + (lane & 15);
    int k = kt * 32 + ((lane >> 4) << 3) + j;
    out[loc] = (k < Kreal) ? (__bf16)W[k * M + m] : (__bf16)0.f;
}

// ---------------- conv1: msg=[pos_src(3), rel(3), pad..32] -> 128 relu -> 128, max over 16 edges
// NB=10 nodes/block; D[m=channel][n=edge] so one node's 16 edges = one MFMA n-tile.
#define NB1 10
__global__ __launch_bounds__(256, 2) void conv1_kernel(
    const float* __restrict__ pos, const int* __restrict__ esrc,
    const __bf16* __restrict__ W1p, const float* __restrict__ b1,
    const __bf16* __restrict__ W2p, const float* __restrict__ b2,
    __bf16* __restrict__ x1)
{
    __shared__ __attribute__((aligned(16))) __bf16 msg[NB1 * 16 * 40];   // 12.8 KB
    __shared__ __attribute__((aligned(16))) __bf16 hid[NB1 * 16 * 136];  // 43.5 KB
    const int tid = threadIdx.x, lane = tid & 63, wave = tid >> 6;
    const int quad = lane >> 4, col = lane & 15;
    const int node0 = blockIdx.x * NB1;

    if (tid < NB1 * 16) {
        int nl = tid >> 4;
        int d = node0 + nl;
        int src = esrc[d * 16 + (tid & 15)];
        float sx = pos[3*src], sy = pos[3*src+1], sz = pos[3*src+2];
        __bf16* row = &msg[tid * 40];
        row[0] = (__bf16)sx; row[1] = (__bf16)sy; row[2] = (__bf16)sz;
        row[3] = (__bf16)(sx - pos[3*d]);
        row[4] = (__bf16)(sy - pos[3*d+1]);
        row[5] = (__bf16)(sz - pos[3*d+2]);
        #pragma unroll
        for (int k = 6; k < 40; k++) row[k] = (__bf16)0.f;
    }
    __syncthreads();

    // phase 1: K=32(pad from 6), out 128 -> 2 mtiles per wave
    {
        bf16x8 A[2]; float bias[2][4];
        #pragma unroll
        for (int i = 0; i < 2; i++) {
            int mtg = wave * 2 + i;
            A[i] = *(const bf16x8*)&W1p[(mtg * 64 + lane) * 8];
            #pragma unroll
            for (int r = 0; r < 4; r++) bias[i][r] = b1[mtg*16 + quad*4 + r];
        }
        for (int n = 0; n < NB1; n++) {
            bf16x8 B = *(const bf16x8*)&msg[(n*16 + col) * 40 + quad*8];
            f32x4 acc[2];
            #pragma unroll
            for (int i = 0; i < 2; i++) {
                acc[i] = (f32x4){bias[i][0], bias[i][1], bias[i][2], bias[i][3]};
                acc[i] = MFMA16(A[i], B, acc[i]);
            }
            #pragma unroll
            for (int i = 0; i < 2; i++) {
                int mtg = wave * 2 + i;
                union { __bf16 h[4]; uint2 u; } pk;
                #pragma unroll
                for (int r = 0; r < 4; r++) pk.h[r] = (__bf16)fmaxf(acc[i][r], 0.f);
                *(uint2*)&hid[(n*16 + col) * 136 + mtg*16 + quad*4] = pk.u;
            }
        }
    }
    __syncthreads();

    // phase 2: K=128 (4 kt), out 128, max over edges -> x1
    {
        bf16x8 A[2][4]; float bias[2][4];
        #pragma unroll
        for (int i = 0; i < 2; i++) {
            int mtg = wave * 2 + i;
            #pragma unroll
            for (int kt = 0; kt < 4; kt++)
                A[i][kt] = *(const bf16x8*)&W2p[((mtg*4 + kt) * 64 + lane) * 8];
            #pragma unroll
            for (int r = 0; r < 4; r++) bias[i][r] = b2[mtg*16 + quad*4 + r];
        }
        for (int n = 0; n < NB1; n++) {
            f32x4 acc[2];
            f32x4 z = {0.f, 0.f, 0.f, 0.f};
            acc[0] = z; acc[1] = z;
            #pragma unroll
            for (int kt = 0; kt < 4; kt++) {
                bf16x8 B = *(const bf16x8*)&hid[(n*16 + col) * 136 + kt*32 + quad*8];
                #pragma unroll
                for (int i = 0; i < 2; i++) acc[i] = MFMA16(A[i][kt], B, acc[i]);
            }
            #pragma unroll
            for (int i = 0; i < 2; i++) {
                float v[4];
                #pragma unroll
                for (int r = 0; r < 4; r++) v[r] = acc[i][r];
                #pragma unroll
                for (int r = 0; r < 4; r++) {
                    v[r] = fmaxf(v[r], __shfl_xor(v[r], 1, 64));
                    v[r] = fmaxf(v[r], __shfl_xor(v[r], 2, 64));
                    v[r] = fmaxf(v[r], __shfl_xor(v[r], 4, 64));
                    v[r] = fmaxf(v[r], __shfl_xor(v[r], 8, 64));
                }
                if (col == 0) {
                    int mtg = wave * 2 + i;
                    union { __bf16 h[4]; uint2 u; } pk;
                    #pragma unroll
                    for (int r = 0; r < 4; r++) pk.h[r] = (__bf16)(v[r] + bias[i][r]);
                    *(uint2*)&x1[(size_t)(node0 + n) * 128 + mtg*16 + quad*4] = pk.u;
                }
            }
        }
    }
}

// ---------------- conv2: msg=[x1_src(128), rel(3), pad..160] -> 256 relu -> 256,
//                  max over edges + fused global max-pool (register running-max)
#define NB2 4
__global__ __launch_bounds__(256, 2) void conv2_kernel(
    const float* __restrict__ pos, const int* __restrict__ esrc,
    const __bf16* __restrict__ x1,
    const __bf16* __restrict__ W1p, const float* __restrict__ b1,
    const __bf16* __restrict__ W2p, const float* __restrict__ b2,
    unsigned int* __restrict__ pooled)
{
    __shared__ __attribute__((aligned(16))) __bf16 msg[NB2 * 16 * 168];  // 21.5 KB
    __shared__ __attribute__((aligned(16))) __bf16 hid[NB2 * 16 * 264];  // 33.8 KB
    __shared__ int ssrc[NB2 * 16];
    const int tid = threadIdx.x, lane = tid & 63, wave = tid >> 6;
    const int quad = lane >> 4, col = lane & 15;
    const int node0 = blockIdx.x * NB2;
    const int R = NB2 * 16;

    if (tid < R) {
        int nl = tid >> 4;
        int d = node0 + nl;
        int src = esrc[d * 16 + (tid & 15)];
        ssrc[tid] = src;
        __bf16* row = &msg[tid * 168];
        row[128] = (__bf16)(pos[3*src]   - pos[3*d]);
        row[129] = (__bf16)(pos[3*src+1] - pos[3*d+1]);
        row[130] = (__bf16)(pos[3*src+2] - pos[3*d+2]);
        #pragma unroll
        for (int k = 131; k < 168; k++) row[k] = (__bf16)0.f;
    }
    __syncthreads();
    for (int u = tid; u < R * 16; u += 256) {
        int row = u >> 4, seg = u & 15;
        *(uint4*)&msg[row * 168 + seg * 8] =
            *(const uint4*)&x1[(size_t)ssrc[row] * 128 + seg * 8];
    }
    __syncthreads();

    // phase 1: K=160 (5 kt), out 256 -> 4 mtiles per wave
    {
        bf16x8 A[4][5]; float bias[4][4];
        #pragma unroll
        for (int i = 0; i < 4; i++) {
            int mtg = wave * 4 + i;
            #pragma unroll
            for (int kt = 0; kt < 5; kt++)
                A[i][kt] = *(const bf16x8*)&W1p[((mtg*5 + kt) * 64 + lane) * 8];
            #pragma unroll
            for (int r = 0; r < 4; r++) bias[i][r] = b1[mtg*16 + quad*4 + r];
        }
        for (int n = 0; n < NB2; n++) {
            f32x4 acc[4];
            #pragma unroll
            for (int i = 0; i < 4; i++)
                acc[i] = (f32x4){bias[i][0], bias[i][1], bias[i][2], bias[i][3]};
            #pragma unroll
            for (int kt = 0; kt < 5; kt++) {
                bf16x8 B = *(const bf16x8*)&msg[(n*16 + col) * 168 + kt*32 + quad*8];
                #pragma unroll
                for (int i = 0; i < 4; i++) acc[i] = MFMA16(A[i][kt], B, acc[i]);
            }
            #pragma unroll
            for (int i = 0; i < 4; i++) {
                int mtg = wave * 4 + i;
                union { __bf16 h[4]; uint2 u; } pk;
                #pragma unroll
                for (int r = 0; r < 4; r++) pk.h[r] = (__bf16)fmaxf(acc[i][r], 0.f);
                *(uint2*)&hid[(n*16 + col) * 264 + mtg*16 + quad*4] = pk.u;
            }
        }
    }
    __syncthreads();

    // phase 2: K=256 (8 kt), out 256, edge-max + node-max in registers, atomic per block
    {
        bf16x8 A[4][8]; float bias[4][4];
        #pragma unroll
        for (int i = 0; i < 4; i++) {
            int mtg = wave * 4 + i;
            #pragma unroll
            for (int kt = 0; kt < 8; kt++)
                A[i][kt] = *(const bf16x8*)&W2p[((mtg*8 + kt) * 64 + lane) * 8];
            #pragma unroll
            for (int r = 0; r < 4; r++) bias[i][r] = b2[mtg*16 + quad*4 + r];
        }
        float runmax[4][4];
        #pragma unroll
        for (int i = 0; i < 4; i++)
            #pragma unroll
            for (int r = 0; r < 4; r++) runmax[i][r] = -3.4e38f;

        auto flush = [&](int g) {
            #pragma unroll
            for (int i = 0; i < 4; i++) {
                #pragma unroll
                for (int r = 0; r < 4; r++) {
                    float v = runmax[i][r];
                    v = fmaxf(v, __shfl_xor(v, 1, 64));
                    v = fmaxf(v, __shfl_xor(v, 2, 64));
                    v = fmaxf(v, __shfl_xor(v, 4, 64));
                    v = fmaxf(v, __shfl_xor(v, 8, 64));
                    if (col == 0) {
                        int c = (wave * 4 + i) * 16 + quad * 4 + r;
                        float val = v + bias[i][r];
                        unsigned u = __float_as_uint(val);
                        u = (u & 0x80000000u) ? ~u : (u | 0x80000000u);
                        atomicMax(&pooled[g * 256 + c], u);
                    }
                }
            }
        };

        int gprev = node0 / NPG;
        for (int n = 0; n < NB2; n++) {
            int g = (node0 + n) / NPG;
            if (g != gprev) {
                flush(gprev);
                #pragma unroll
                for (int i = 0; i < 4; i++)
                    #pragma unroll
                    for (int r = 0; r < 4; r++) runmax[i][r] = -3.4e38f;
                gprev = g;
            }
            f32x4 acc[4];
            f32x4 z = {0.f, 0.f, 0.f, 0.f};
            #pragma unroll
            for (int i = 0; i < 4; i++) acc[i] = z;
            #pragma unroll
            for (int kt = 0; kt < 8; kt++) {
                bf16x8 B = *(const bf16x8*)&hid[(n*16 + col) * 264 + kt*32 + quad*8];
                #pragma unroll
                for (int i = 0; i < 4; i++) acc[i] = MFMA16(A[i][kt], B, acc[i]);
            }
            #pragma unroll
            for (int i = 0; i < 4; i++)
                #pragma unroll
                for (int r = 0; r < 4; r++)
                    runmax[i][r] = fmaxf(runmax[i][r], acc[i][r]);
        }
        flush(gprev);
    }
}

// ---------------- head (fp32, tiny)
__global__ __launch_bounds__(256) void head_kernel(
    const unsigned int* __restrict__ pooled,
    const float* __restrict__ fc1_W, const float* __restrict__ fc1_b,
    const float* __restrict__ fc2_W, const float* __restrict__ fc2_b,
    const float* __restrict__ lab_W, const float* __restrict__ lab_b,
    const float* __restrict__ box_W, const float* __restrict__ box_b,
    float* __restrict__ out)
{
    __shared__ float p [GRAPHS][256];
    __shared__ float h1[GRAPHS][256];
    __shared__ float h2[GRAPHS][128];
    const int c = threadIdx.x;

    #pragma unroll
    for (int g = 0; g < GRAPHS; g++) {
        unsigned u = pooled[g*256 + c];
        u = (u & 0x80000000u) ? (u & 0x7fffffffu) : ~u;
        p[g][c] = __uint_as_float(u);
    }
    __syncthreads();

    float acc[GRAPHS];
    float bb = fc1_b[c];
    #pragma unroll
    for (int g = 0; g < GRAPHS; g++) acc[g] = bb;
    for (int k = 0; k < 256; k++) {
        float w = fc1_W[k*256 + c];
        #pragma unroll
        for (int g = 0; g < GRAPHS; g++) acc[g] += p[g][k] * w;
    }
    #pragma unroll
    for (int g = 0; g < GRAPHS; g++) h1[g][c] = fmaxf(acc[g], 0.0f);
    __syncthreads();

    if (c < 128) {
        float bb2 = fc2_b[c];
        #pragma unroll
        for (int g = 0; g < GRAPHS; g++) acc[g] = bb2;
        for (int k = 0; k < 256; k++) {
            float w = fc2_W[k*128 + c];
            #pragma unroll
            for (int g = 0; g < GRAPHS; g++) acc[g] += h1[g][k] * w;
        }
        #pragma unroll
        for (int g = 0; g < GRAPHS; g++) h2[g][c] = fmaxf(acc[g], 0.0f);
    }
    __syncthreads();

    if (c < 160) {
        int g = c / 10, j = c % 10;
        float a = lab_b[j];
        for (int k = 0; k < 128; k++) a += h2[g][k] * lab_W[k*10 + j];
        out[c] = a;
    } else {
        int t = c - 160;
        int g = t / 6, j = t % 6;
        float a = box_b[j];
        for (int k = 0; k < 128; k++) a += h2[g][k] * box_W[k*6 + j];
        out[160 + t] = a;
    }
}

extern "C" void kernel_launch(void* const* d_in, const int* in_sizes, int n_in,
                              void* d_out, int out_size, void* d_ws, size_t ws_size,
                              hipStream_t stream) {
    const float* pos   = (const float*)d_in[0];
    const int*   esrc  = (const int*)  d_in[1];
    const float* c1W1 = (const float*)d_in[4];
    const float* c1b1 = (const float*)d_in[5];
    const float* c1W2 = (const float*)d_in[6];
    const float* c1b2 = (const float*)d_in[7];
    const float* c2W1 = (const float*)d_in[8];
    const float* c2b1 = (const float*)d_in[9];
    const float* c2W2 = (const float*)d_in[10];
    const float* c2b2 = (const float*)d_in[11];
    const float* fc1W = (const float*)d_in[12];
    const float* fc1b = (const float*)d_in[13];
    const float* fc2W = (const float*)d_in[14];
    const float* fc2b = (const float*)d_in[15];
    const float* labW = (const float*)d_in[16];
    const float* labb = (const float*)d_in[17];
    const float* boxW = (const float*)d_in[18];
    const float* boxb = (const float*)d_in[19];

    __bf16* wsb = (__bf16*)d_ws;
    __bf16* x1  = wsb + OFF_X1;
    __bf16* p1  = wsb + OFF_P1;
    __bf16* p2  = wsb + OFF_P2;
    __bf16* p3  = wsb + OFF_P3;
    __bf16* p4  = wsb + OFF_P4;
    unsigned int* pooled = (unsigned int*)((char*)d_ws + OFF_POOL_BYTES);

    hipMemsetAsync(pooled, 0, GRAPHS * 256 * sizeof(unsigned int), stream);

    pack_weights<<<496, 256, 0, stream>>>(c1W1, c1W2, c2W1, c2W2, p1, p2, p3, p4);
    conv1_kernel<<<N_NODES / NB1, 256, 0, stream>>>(pos, esrc, p1, c1b1, p2, c1b2, x1);
    conv2_kernel<<<N_NODES / NB2, 256, 0, stream>>>(pos, esrc, x1, p3, c2b1, p4, c2b2, pooled);
    head_kernel<<<1, 256, 0, stream>>>(pooled, fc1W, fc1b, fc2W, fc2b,
                                       labW, labb, boxW, boxb, (float*)d_out);
}

// Round 3
// 259.368 us; speedup vs baseline: 6.1175x; 1.3775x over previous
//
#include <hip/hip_runtime.h>

#define N_NODES 20000
#define DEG 16
#define GRAPHS 16
#define NPG 1250

typedef __bf16 bf16x8 __attribute__((ext_vector_type(8)));
typedef float f32x4 __attribute__((ext_vector_type(4)));
#define MFMA16(a, b, c) __builtin_amdgcn_mfma_f32_16x16x32_bf16(a, b, c, 0, 0, 0)

// ---- workspace layout (bf16 element offsets) ----
#define OFF_X1    0            // x1 [20000][128] bf16
#define OFF_P1    2560000      // c1W1 packed: MT=8  KT=1 -> 4096
#define OFF_P2    2564096      // c1W2 packed: MT=8  KT=4 -> 16384
#define OFF_P3    2580480      // c2W1 packed: MT=16 KT=5 -> 40960
#define OFF_P4    2621440      // c2W2 packed: MT=16 KT=8 -> 65536
#define OFF_POOL_BYTES 5373952 // pooled u32[16*256]

// Frag layout (identical for MFMA A-role and B-role of mfma_f32_16x16x32_bf16):
//   frag[((t*KT+kt)*64+lane)*8 + j] = X[k = kt*32 + (lane>>4)*8 + j][idx = lane&15]
__global__ __launch_bounds__(256) void pack_weights(
    const float* __restrict__ c1W1, const float* __restrict__ c1W2,
    const float* __restrict__ c2W1, const float* __restrict__ c2W2,
    __bf16* __restrict__ p1, __bf16* __restrict__ p2,
    __bf16* __restrict__ p3, __bf16* __restrict__ p4,
    unsigned int* __restrict__ pooled)
{
    int t = blockIdx.x * 256 + threadIdx.x;
    if (t < GRAPHS * 256) pooled[t] = 0u;   // flipped(-inf) == 0
    const float* W; __bf16* out; int M, Kreal, KT, loc;
    if      (t <   4096) { W = c1W1; out = p1; M = 128; Kreal =   6; KT = 1; loc = t; }
    else if (t <  20480) { W = c1W2; out = p2; M = 128; Kreal = 128; KT = 4; loc = t - 4096; }
    else if (t <  61440) { W = c2W1; out = p3; M = 256; Kreal = 131; KT = 5; loc = t - 20480; }
    else if (t < 126976) { W = c2W2; out = p4; M = 256; Kreal = 256; KT = 8; loc = t - 61440; }
    else return;
    int j = loc & 7, lane = (loc >> 3) & 63, rest = loc >> 9;
    int kt = rest % KT, mt = rest / KT;
    int m = mt * 16 + (lane & 15);
    int k = kt * 32 + ((lane >> 4) << 3) + j;
    out[loc] = (k < Kreal) ? (__bf16)W[k * M + m] : (__bf16)0.f;
}

// =================== conv1 ===================
// 500 blocks x 40 contiguous nodes (5 tiles of NB1=8). Weights register-resident.
// p1: D[ch][edge] (A=W1 frags, B=msg frags). p2: D[edge][ch] (A=hid frags, B=W2 frags),
// edge-max = 3 reg-fmax + shfl_xor(16) + shfl_xor(32).
#define NB1 8
__global__ __launch_bounds__(256, 3) void conv1_kernel(
    const float* __restrict__ pos, const int* __restrict__ esrc,
    const __bf16* __restrict__ W1p, const float* __restrict__ b1,
    const __bf16* __restrict__ W2p, const float* __restrict__ b2,
    __bf16* __restrict__ x1)
{
    __shared__ __attribute__((aligned(16))) __bf16 msgF[NB1 * 64 * 8];      // 8 KB
    __shared__ __attribute__((aligned(16))) __bf16 hidF[NB1 * 4 * 64 * 8];  // 32 KB
    const int tid = threadIdx.x, lane = tid & 63, wave = tid >> 6;
    const int quad = lane >> 4, col = lane & 15;
    const int base = blockIdx.x * 40;

    // resident weights
    bf16x8 A1[2], B2[2][4];
    f32x4 bias1[2];
    float b2v[2];
    #pragma unroll
    for (int i = 0; i < 2; i++) {
        int mtg = wave * 2 + i;
        A1[i] = *(const bf16x8*)&W1p[(mtg * 64 + lane) * 8];
        bias1[i] = *(const f32x4*)&b1[mtg * 16 + quad * 4];
        #pragma unroll
        for (int kt = 0; kt < 4; kt++)
            B2[i][kt] = *(const bf16x8*)&W2p[((mtg * 4 + kt) * 64 + lane) * 8];
        b2v[i] = b2[mtg * 16 + col];
    }

    for (int t = 0; t < 5; t++) {
        const int node0 = base + t * NB1;
        // ---- stage msg frags: k = quad*8+j, real k<6 on quad 0 ----
        #pragma unroll
        for (int s = 0; s < 2; s++) {
            int u = tid + 256 * s;          // < 512
            int nl = u >> 6, l = u & 63;
            int q = l >> 4, c = l & 15;
            bf16x8 v;
            if (q == 0) {
                int d = node0 + nl;
                int src = esrc[d * 16 + c];
                float sx = pos[3*src], sy = pos[3*src+1], sz = pos[3*src+2];
                v[0] = (__bf16)sx; v[1] = (__bf16)sy; v[2] = (__bf16)sz;
                v[3] = (__bf16)(sx - pos[3*d]);
                v[4] = (__bf16)(sy - pos[3*d+1]);
                v[5] = (__bf16)(sz - pos[3*d+2]);
                v[6] = (__bf16)0.f; v[7] = (__bf16)0.f;
            } else {
                #pragma unroll
                for (int j = 0; j < 8; j++) v[j] = (__bf16)0.f;
            }
            *(bf16x8*)&msgF[(nl * 64 + l) * 8] = v;
        }
        __syncthreads();

        // ---- phase 1: D[ch][edge], write hid in frag layout ----
        #pragma unroll
        for (int nl = 0; nl < NB1; nl++) {
            bf16x8 B = *(const bf16x8*)&msgF[(nl * 64 + lane) * 8];
            #pragma unroll
            for (int i = 0; i < 2; i++) {
                int mtg = wave * 2 + i;
                f32x4 acc = bias1[i];
                acc = MFMA16(A1[i], B, acc);
                union { __bf16 h[4]; uint2 u; } pk;
                #pragma unroll
                for (int r = 0; r < 4; r++) pk.h[r] = (__bf16)fmaxf(acc[r], 0.f);
                int kt2 = mtg >> 1;
                int lane2 = ((mtg * 2 + (quad >> 1)) & 3) * 16 + col;
                int j0 = (quad & 1) * 4;
                *(uint2*)&hidF[((nl * 4 + kt2) * 64 + lane2) * 8 + j0] = pk.u;
            }
        }
        __syncthreads();

        // ---- phase 2: D[edge][ch], edge-max, write x1 ----
        #pragma unroll
        for (int nl = 0; nl < NB1; nl++) {
            bf16x8 hA[4];
            #pragma unroll
            for (int kt = 0; kt < 4; kt++)
                hA[kt] = *(const bf16x8*)&hidF[((nl * 4 + kt) * 64 + lane) * 8];
            f32x4 acc[2];
            f32x4 z = {0.f, 0.f, 0.f, 0.f};
            acc[0] = z; acc[1] = z;
            #pragma unroll
            for (int kt = 0; kt < 4; kt++) {
                #pragma unroll
                for (int i = 0; i < 2; i++) acc[i] = MFMA16(hA[kt], B2[i][kt], acc[i]);
            }
            #pragma unroll
            for (int i = 0; i < 2; i++) {
                int mtg = wave * 2 + i;
                float m = fmaxf(fmaxf(acc[i][0], acc[i][1]), fmaxf(acc[i][2], acc[i][3]));
                m = fmaxf(m, __shfl_xor(m, 16));
                m = fmaxf(m, __shfl_xor(m, 32));
                if (lane < 16)
                    x1[(size_t)(node0 + nl) * 128 + mtg * 16 + lane] = (__bf16)(m + b2v[i]);
            }
        }
        __syncthreads();
    }
}

// =================== conv2 ===================
// 250 blocks x 512 threads x 80 contiguous nodes (40 tiles of NB2=2).
// Producer-consumer: waves 0-3 = layer1 (A1 resident, 80 VGPR), waves 4-7 = layer2
// (A2 resident, 128 VGPR). Double-buffered msg/hid frags, ONE barrier per tile.
#define NB2 2
#define NT2 40
__global__ __launch_bounds__(512, 2) void conv2_kernel(
    const float* __restrict__ pos, const int* __restrict__ esrc,
    const __bf16* __restrict__ x1,
    const __bf16* __restrict__ W1p, const float* __restrict__ b1,
    const __bf16* __restrict__ W2p, const float* __restrict__ b2,
    unsigned int* __restrict__ pooled)
{
    __shared__ __attribute__((aligned(16))) __bf16 msgF[2][NB2 * 5 * 64 * 8];  // 2x10 KB
    __shared__ __attribute__((aligned(16))) __bf16 hidF[2][NB2 * 8 * 64 * 8];  // 2x16 KB
    const int tid = threadIdx.x, lane = tid & 63, wave = tid >> 6;
    const int quad = lane >> 4, col = lane & 15;
    const int base = blockIdx.x * (NB2 * NT2);

    if (wave < 4) {
        // ===== producer: layer 1 =====
        bf16x8 A1[4][5];
        f32x4 bias1[4];
        #pragma unroll
        for (int i = 0; i < 4; i++) {
            int mtg = wave * 4 + i;
            #pragma unroll
            for (int kt = 0; kt < 5; kt++)
                A1[i][kt] = *(const bf16x8*)&W1p[((mtg * 5 + kt) * 64 + lane) * 8];
            bias1[i] = *(const f32x4*)&b1[mtg * 16 + quad * 4];
        }
        // stage tile 0 into buffer 0
        #pragma unroll
        for (int s = 0; s < 3; s++) {
            int u = tid + 256 * s;
            if (u < NB2 * 5 * 64) {
                int nl = u / 320, rr = u % 320;
                int kt = rr >> 6, l = rr & 63;
                int q = l >> 4, c = l & 15;
                int d = base + nl;
                if (kt < 4) {
                    int src = esrc[d * 16 + c];
                    *(uint4*)&msgF[0][((nl * 5 + kt) * 64 + l) * 8] =
                        *(const uint4*)&x1[(size_t)src * 128 + kt * 32 + q * 8];
                } else {
                    bf16x8 v;
                    #pragma unroll
                    for (int j = 0; j < 8; j++) v[j] = (__bf16)0.f;
                    if (q == 0) {
                        int src = esrc[d * 16 + c];
                        v[0] = (__bf16)(pos[3*src]   - pos[3*d]);
                        v[1] = (__bf16)(pos[3*src+1] - pos[3*d+1]);
                        v[2] = (__bf16)(pos[3*src+2] - pos[3*d+2]);
                    }
                    *(bf16x8*)&msgF[0][((nl * 5 + kt) * 64 + l) * 8] = v;
                }
            }
        }
        __syncthreads();

        for (int k = 0; k < NT2; k++) {
            const int buf = k & 1;
            // stage tile k+1 into buf^1 (global loads overlap MFMA below)
            if (k + 1 < NT2) {
                const int n0 = base + (k + 1) * NB2;
                #pragma unroll
                for (int s = 0; s < 3; s++) {
                    int u = tid + 256 * s;
                    if (u < NB2 * 5 * 64) {
                        int nl = u / 320, rr = u % 320;
                        int kt = rr >> 6, l = rr & 63;
                        int q = l >> 4, c = l & 15;
                        int d = n0 + nl;
                        if (kt < 4) {
                            int src = esrc[d * 16 + c];
                            *(uint4*)&msgF[buf ^ 1][((nl * 5 + kt) * 64 + l) * 8] =
                                *(const uint4*)&x1[(size_t)src * 128 + kt * 32 + q * 8];
                        } else {
                            bf16x8 v;
                            #pragma unroll
                            for (int j = 0; j < 8; j++) v[j] = (__bf16)0.f;
                            if (q == 0) {
                                int src = esrc[d * 16 + c];
                                v[0] = (__bf16)(pos[3*src]   - pos[3*d]);
                                v[1] = (__bf16)(pos[3*src+1] - pos[3*d+1]);
                                v[2] = (__bf16)(pos[3*src+2] - pos[3*d+2]);
                            }
                            *(bf16x8*)&msgF[buf ^ 1][((nl * 5 + kt) * 64 + l) * 8] = v;
                        }
                    }
                }
            }
            // compute layer1 for tile k from msgF[buf] -> hidF[buf]
            #pragma unroll
            for (int nl = 0; nl < NB2; nl++) {
                bf16x8 B[5];
                #pragma unroll
                for (int kt = 0; kt < 5; kt++)
                    B[kt] = *(const bf16x8*)&msgF[buf][((nl * 5 + kt) * 64 + lane) * 8];
                #pragma unroll
                for (int i = 0; i < 4; i++) {
                    int mtg = wave * 4 + i;
                    f32x4 acc = bias1[i];
                    #pragma unroll
                    for (int kt = 0; kt < 5; kt++) acc = MFMA16(A1[i][kt], B[kt], acc);
                    union { __bf16 h[4]; uint2 u; } pk;
                    #pragma unroll
                    for (int r = 0; r < 4; r++) pk.h[r] = (__bf16)fmaxf(acc[r], 0.f);
                    int kt2 = mtg >> 1;
                    int lane2 = ((mtg * 2 + (quad >> 1)) & 3) * 16 + col;
                    int j0 = (quad & 1) * 4;
                    *(uint2*)&hidF[buf][((nl * 8 + kt2) * 64 + lane2) * 8 + j0] = pk.u;
                }
            }
            __syncthreads();
        }
    } else {
        // ===== consumer: layer 2 + fused global max-pool =====
        const int wv = wave - 4;
        bf16x8 A2[4][8];
        #pragma unroll
        for (int i = 0; i < 4; i++) {
            int mtg = wv * 4 + i;
            #pragma unroll
            for (int kt = 0; kt < 8; kt++)
                A2[i][kt] = *(const bf16x8*)&W2p[((mtg * 8 + kt) * 64 + lane) * 8];
        }
        f32x4 runmax[4];
        #pragma unroll
        for (int i = 0; i < 4; i++)
            #pragma unroll
            for (int r = 0; r < 4; r++) runmax[i][r] = -3.4e38f;

        auto flushfn = [&](int g) {
            #pragma unroll
            for (int i = 0; i < 4; i++) {
                #pragma unroll
                for (int r = 0; r < 4; r++) {
                    float v = runmax[i][r];
                    v = fmaxf(v, __shfl_xor(v, 1));
                    v = fmaxf(v, __shfl_xor(v, 2));
                    v = fmaxf(v, __shfl_xor(v, 4));
                    v = fmaxf(v, __shfl_xor(v, 8));
                    if (col == 0) {
                        int c = (wv * 4 + i) * 16 + quad * 4 + r;
                        float val = v + b2[c];          // rare: load bias at flush
                        unsigned u = __float_as_uint(val);
                        u = (u & 0x80000000u) ? ~u : (u | 0x80000000u);
                        atomicMax(&pooled[g * 256 + c], u);
                    }
                }
            }
        };

        __syncthreads();   // matches producer's post-stage barrier
        int gprev = base / NPG;
        for (int k = 0; k < NT2; k++) {
            if (k > 0) {
                const int buf1 = (k - 1) & 1;
                const int n0 = base + (k - 1) * NB2;
                int g = n0 / NPG;
                if (g != gprev) {
                    flushfn(gprev);
                    #pragma unroll
                    for (int i = 0; i < 4; i++)
                        #pragma unroll
                        for (int r = 0; r < 4; r++) runmax[i][r] = -3.4e38f;
                    gprev = g;
                }
                #pragma unroll
                for (int nl = 0; nl < NB2; nl++) {
                    bf16x8 hB[8];
                    #pragma unroll
                    for (int kt = 0; kt < 8; kt++)
                        hB[kt] = *(const bf16x8*)&hidF[buf1][((nl * 8 + kt) * 64 + lane) * 8];
                    f32x4 acc[4];
                    f32x4 z = {0.f, 0.f, 0.f, 0.f};
                    #pragma unroll
                    for (int i = 0; i < 4; i++) acc[i] = z;
                    #pragma unroll
                    for (int kt = 0; kt < 8; kt++) {
                        #pragma unroll
                        for (int i = 0; i < 4; i++) acc[i] = MFMA16(A2[i][kt], hB[kt], acc[i]);
                    }
                    #pragma unroll
                    for (int i = 0; i < 4; i++)
                        #pragma unroll
                        for (int r = 0; r < 4; r++)
                            runmax[i][r] = fmaxf(runmax[i][r], acc[i][r]);
                }
            }
            __syncthreads();
        }
        // final tile (NT2-1) sits in hidF[(NT2-1)&1]; no more barriers needed
        {
            const int buf1 = (NT2 - 1) & 1;
            const int n0 = base + (NT2 - 1) * NB2;
            int g = n0 / NPG;
            if (g != gprev) {
                flushfn(gprev);
                #pragma unroll
                for (int i = 0; i < 4; i++)
                    #pragma unroll
                    for (int r = 0; r < 4; r++) runmax[i][r] = -3.4e38f;
                gprev = g;
            }
            #pragma unroll
            for (int nl = 0; nl < NB2; nl++) {
                bf16x8 hB[8];
                #pragma unroll
                for (int kt = 0; kt < 8; kt++)
                    hB[kt] = *(const bf16x8*)&hidF[buf1][((nl * 8 + kt) * 64 + lane) * 8];
                f32x4 acc[4];
                f32x4 z = {0.f, 0.f, 0.f, 0.f};
                #pragma unroll
                for (int i = 0; i < 4; i++) acc[i] = z;
                #pragma unroll
                for (int kt = 0; kt < 8; kt++) {
                    #pragma unroll
                    for (int i = 0; i < 4; i++) acc[i] = MFMA16(A2[i][kt], hB[kt], acc[i]);
                }
                #pragma unroll
                for (int i = 0; i < 4; i++)
                    #pragma unroll
                    for (int r = 0; r < 4; r++)
                        runmax[i][r] = fmaxf(runmax[i][r], acc[i][r]);
            }
            flushfn(gprev);
        }
    }
}

// =================== head (tiny, fp32) ===================
__global__ __launch_bounds__(256) void head_kernel(
    const unsigned int* __restrict__ pooled,
    const float* __restrict__ fc1_W, const float* __restrict__ fc1_b,
    const float* __restrict__ fc2_W, const float* __restrict__ fc2_b,
    const float* __restrict__ lab_W, const float* __restrict__ lab_b,
    const float* __restrict__ box_W, const float* __restrict__ box_b,
    float* __restrict__ out)
{
    __shared__ float p [GRAPHS][256];
    __shared__ float h1[GRAPHS][256];
    __shared__ float h2[GRAPHS][128];
    const int c = threadIdx.x;

    #pragma unroll
    for (int g = 0; g < GRAPHS; g++) {
        unsigned u = pooled[g*256 + c];
        u = (u & 0x80000000u) ? (u & 0x7fffffffu) : ~u;
        p[g][c] = __uint_as_float(u);
    }
    __syncthreads();

    float acc[GRAPHS];
    float bb = fc1_b[c];
    #pragma unroll
    for (int g = 0; g < GRAPHS; g++) acc[g] = bb;
    for (int k = 0; k < 256; k++) {
        float w = fc1_W[k*256 + c];
        #pragma unroll
        for (int g = 0; g < GRAPHS; g++) acc[g] += p[g][k] * w;
    }
    #pragma unroll
    for (int g = 0; g < GRAPHS; g++) h1[g][c] = fmaxf(acc[g], 0.0f);
    __syncthreads();

    if (c < 128) {
        float bb2 = fc2_b[c];
        #pragma unroll
        for (int g = 0; g < GRAPHS; g++) acc[g] = bb2;
        for (int k = 0; k < 256; k++) {
            float w = fc2_W[k*128 + c];
            #pragma unroll
            for (int g = 0; g < GRAPHS; g++) acc[g] += h1[g][k] * w;
        }
        #pragma unroll
        for (int g = 0; g < GRAPHS; g++) h2[g][c] = fmaxf(acc[g], 0.0f);
    }
    __syncthreads();

    if (c < 160) {
        int g = c / 10, j = c % 10;
        float a = lab_b[j];
        for (int k = 0; k < 128; k++) a += h2[g][k] * lab_W[k*10 + j];
        out[c] = a;
    } else {
        int t = c - 160;
        int g = t / 6, j = t % 6;
        float a = box_b[j];
        for (int k = 0; k < 128; k++) a += h2[g][k] * box_W[k*6 + j];
        out[160 + t] = a;
    }
}

extern "C" void kernel_launch(void* const* d_in, const int* in_sizes, int n_in,
                              void* d_out, int out_size, void* d_ws, size_t ws_size,
                              hipStream_t stream) {
    const float* pos   = (const float*)d_in[0];
    const int*   esrc  = (const int*)  d_in[1];
    const float* c1W1 = (const float*)d_in[4];
    const float* c1b1 = (const float*)d_in[5];
    const float* c1W2 = (const float*)d_in[6];
    const float* c1b2 = (const float*)d_in[7];
    const float* c2W1 = (const float*)d_in[8];
    const float* c2b1 = (const float*)d_in[9];
    const float* c2W2 = (const float*)d_in[10];
    const float* c2b2 = (const float*)d_in[11];
    const float* fc1W = (const float*)d_in[12];
    const float* fc1b = (const float*)d_in[13];
    const float* fc2W = (const float*)d_in[14];
    const float* fc2b = (const float*)d_in[15];
    const float* labW = (const float*)d_in[16];
    const float* labb = (const float*)d_in[17];
    const float* boxW = (const float*)d_in[18];
    const float* boxb = (const float*)d_in[19];

    __bf16* wsb = (__bf16*)d_ws;
    __bf16* x1  = wsb + OFF_X1;
    __bf16* p1  = wsb + OFF_P1;
    __bf16* p2  = wsb + OFF_P2;
    __bf16* p3  = wsb + OFF_P3;
    __bf16* p4  = wsb + OFF_P4;
    unsigned int* pooled = (unsigned int*)((char*)d_ws + OFF_POOL_BYTES);

    pack_weights<<<496, 256, 0, stream>>>(c1W1, c1W2, c2W1, c2W2, p1, p2, p3, p4, pooled);
    conv1_kernel<<<500, 256, 0, stream>>>(pos, esrc, p1, c1b1, p2, c1b2, x1);
    conv2_kernel<<<250, 512, 0, stream>>>(pos, esrc, x1, p3, c2b1, p4, c2b2, pooled);
    head_kernel<<<1, 256, 0, stream>>>(pooled, fc1W, fc1b, fc2W, fc2b,
                                       labW, labb, boxW, boxb, (float*)d_out);
}